// Round 3
// baseline (1384.479 us; speedup 1.0000x reference)
//
#include <hip/hip_runtime.h>

// ============================================================================
// L4maAttention on MI355X (gfx950) — round 3
// DECISIVE CHANGE vs rounds 1-2 (NaN): inputs are FLOAT32 per the reference
// file (jnp.float32 everywhere). Rounds 1-2 read them as bf16 u16 pairs ->
// random bit patterns -> NaN in K=4096 accumulation. Now: fp32 loads, RNE
// convert to bf16 at staging, bf16 MFMA compute, fp32 final output.
// Intermediates (qbuf/kbuf/vbuf/vtg/obuf) remain bf16.
// Pipeline: gemm(Q) gemm(K) gemm(V) -> rope -> vt_build -> attn -> gemm(O)
// ============================================================================

typedef unsigned short u16;
typedef __attribute__((ext_vector_type(8))) unsigned short u16x8;
typedef __attribute__((ext_vector_type(8))) __bf16 bf16x8;
typedef __attribute__((ext_vector_type(4))) float f32x4;

#define PREFIX 3072
#define FRESH0 192   // PREFIX/16

__device__ __forceinline__ float b2f(u16 s) {
  union { unsigned u; float f; } v; v.u = ((unsigned)s) << 16; return v.f;
}
__device__ __forceinline__ u16 f2b(float f) {
  union { float f; unsigned u; } v; v.f = f;
  return (u16)((v.u + 0x7FFFu + ((v.u >> 16) & 1u)) >> 16);
}
__device__ __forceinline__ bf16x8 asbf(u16x8 u) { return __builtin_bit_cast(bf16x8, u); }
__device__ __forceinline__ u16x8 cvt8(f32x4 a, f32x4 b) {
  u16x8 r;
#pragma unroll
  for (int i = 0; i < 4; i++) { r[i] = f2b(a[i]); r[4 + i] = f2b(b[i]); }
  return r;
}

__device__ __forceinline__ void gll16(const u16* g, u16* l) {
  __builtin_amdgcn_global_load_lds(
      (const __attribute__((address_space(1))) unsigned*)g,
      (__attribute__((address_space(3))) unsigned*)l, 16, 0, 0);
}

// ---------------------------------------------------------------------------
// GEMM A(f32)[M][K] * W(f32)[N][K]^T -> C(bf16)[M][N].  128x128 tile, BK=32.
// ---------------------------------------------------------------------------
__global__ __launch_bounds__(256) void gemm_ff(const float* __restrict__ A,
                                               const float* __restrict__ W,
                                               u16* __restrict__ C,
                                               int N, int K) {
  __shared__ __align__(16) u16 lA[128 * 32];
  __shared__ __align__(16) u16 lB[128 * 32];
  const int tid = threadIdx.x;
  const int wave = tid >> 6, lane = tid & 63;
  const int lr = lane & 15, quad = lane >> 4;
  const int m0 = blockIdx.y * 128, n0 = blockIdx.x * 128;
  const int wm = (wave & 1) * 64, wn = (wave >> 1) * 64;

  const float* aP0 = A + (size_t)(m0 + (tid >> 2)) * K + (tid & 3) * 8;
  const float* aP1 = aP0 + (size_t)64 * K;
  const float* bP0 = W + (size_t)(n0 + (tid >> 2)) * K + (tid & 3) * 8;
  const float* bP1 = bP0 + (size_t)64 * K;
  u16* la0 = &lA[(tid >> 2) * 32 + (tid & 3) * 8];
  u16* la1 = la0 + 64 * 32;
  u16* lb0 = &lB[(tid >> 2) * 32 + (tid & 3) * 8];
  u16* lb1 = lb0 + 64 * 32;

  f32x4 acc[4][4];
#pragma unroll
  for (int i = 0; i < 4; i++)
#pragma unroll
    for (int j = 0; j < 4; j++) acc[i][j] = (f32x4){0.f, 0.f, 0.f, 0.f};

  for (int k0 = 0; k0 < K; k0 += 32) {
    f32x4 a0 = *(const f32x4*)aP0, a0b = *(const f32x4*)(aP0 + 4);
    f32x4 a1 = *(const f32x4*)aP1, a1b = *(const f32x4*)(aP1 + 4);
    f32x4 b0 = *(const f32x4*)bP0, b0b = *(const f32x4*)(bP0 + 4);
    f32x4 b1 = *(const f32x4*)bP1, b1b = *(const f32x4*)(bP1 + 4);
    aP0 += 32; aP1 += 32; bP0 += 32; bP1 += 32;
    __syncthreads();           // prior iteration's LDS reads done
    *(u16x8*)la0 = cvt8(a0, a0b);
    *(u16x8*)la1 = cvt8(a1, a1b);
    *(u16x8*)lb0 = cvt8(b0, b0b);
    *(u16x8*)lb1 = cvt8(b1, b1b);
    __syncthreads();
    bf16x8 af[4], bfr[4];
#pragma unroll
    for (int i = 0; i < 4; i++)
      af[i] = asbf(*(const u16x8*)&lA[(wm + i * 16 + lr) * 32 + quad * 8]);
#pragma unroll
    for (int i = 0; i < 4; i++)
      bfr[i] = asbf(*(const u16x8*)&lB[(wn + i * 16 + lr) * 32 + quad * 8]);
#pragma unroll
    for (int mi = 0; mi < 4; mi++)
#pragma unroll
      for (int ni = 0; ni < 4; ni++)
        acc[mi][ni] = __builtin_amdgcn_mfma_f32_16x16x32_bf16(af[mi], bfr[ni], acc[mi][ni], 0, 0, 0);
  }

  // C/D layout: col = lane&15, row = quad*4 + reg
#pragma unroll
  for (int mi = 0; mi < 4; mi++)
#pragma unroll
    for (int ni = 0; ni < 4; ni++) {
      int row = m0 + wm + mi * 16 + quad * 4;
      int col = n0 + wn + ni * 16 + lr;
#pragma unroll
      for (int r = 0; r < 4; r++) C[(size_t)(row + r) * N + col] = f2b(acc[mi][ni][r]);
    }
}

// ---------------------------------------------------------------------------
// GEMM A(bf16)[M][K] * W(f32)[N][K]^T -> C(f32)[M][N].  For O-projection.
// ---------------------------------------------------------------------------
__global__ __launch_bounds__(256) void gemm_bf(const u16* __restrict__ A,
                                               const float* __restrict__ W,
                                               float* __restrict__ C,
                                               int N, int K) {
  __shared__ __align__(16) u16 lA[128 * 32];
  __shared__ __align__(16) u16 lB[128 * 32];
  const int tid = threadIdx.x;
  const int wave = tid >> 6, lane = tid & 63;
  const int lr = lane & 15, quad = lane >> 4;
  const int m0 = blockIdx.y * 128, n0 = blockIdx.x * 128;
  const int wm = (wave & 1) * 64, wn = (wave >> 1) * 64;

  const u16* aS0 = A + (size_t)(m0 + (tid >> 2)) * K + (tid & 3) * 8;
  const u16* aS1 = aS0 + (size_t)64 * K;
  const float* bP0 = W + (size_t)(n0 + (tid >> 2)) * K + (tid & 3) * 8;
  const float* bP1 = bP0 + (size_t)64 * K;
  u16* lA0 = lA + wave * 512;   // wave-uniform LDS base for global_load_lds
  u16* lA1 = lA + 2048 + wave * 512;
  u16* lb0 = &lB[(tid >> 2) * 32 + (tid & 3) * 8];
  u16* lb1 = lb0 + 64 * 32;

  f32x4 acc[4][4];
#pragma unroll
  for (int i = 0; i < 4; i++)
#pragma unroll
    for (int j = 0; j < 4; j++) acc[i][j] = (f32x4){0.f, 0.f, 0.f, 0.f};

  for (int k0 = 0; k0 < K; k0 += 32) {
    f32x4 b0 = *(const f32x4*)bP0, b0b = *(const f32x4*)(bP0 + 4);
    f32x4 b1 = *(const f32x4*)bP1, b1b = *(const f32x4*)(bP1 + 4);
    bP0 += 32; bP1 += 32;
    __syncthreads();
    gll16(aS0, lA0); gll16(aS1, lA1);
    aS0 += 32; aS1 += 32;
    *(u16x8*)lb0 = cvt8(b0, b0b);
    *(u16x8*)lb1 = cvt8(b1, b1b);
    __syncthreads();
    bf16x8 af[4], bfr[4];
#pragma unroll
    for (int i = 0; i < 4; i++)
      af[i] = asbf(*(const u16x8*)&lA[(wm + i * 16 + lr) * 32 + quad * 8]);
#pragma unroll
    for (int i = 0; i < 4; i++)
      bfr[i] = asbf(*(const u16x8*)&lB[(wn + i * 16 + lr) * 32 + quad * 8]);
#pragma unroll
    for (int mi = 0; mi < 4; mi++)
#pragma unroll
      for (int ni = 0; ni < 4; ni++)
        acc[mi][ni] = __builtin_amdgcn_mfma_f32_16x16x32_bf16(af[mi], bfr[ni], acc[mi][ni], 0, 0, 0);
  }

#pragma unroll
  for (int mi = 0; mi < 4; mi++)
#pragma unroll
    for (int ni = 0; ni < 4; ni++) {
      int row = m0 + wm + mi * 16 + quad * 4;
      int col = n0 + wn + ni * 16 + lr;
#pragma unroll
      for (int r = 0; r < 4; r++) C[(size_t)(row + r) * N + col] = acc[mi][ni][r];
    }
}

// ---------------------------------------------------------------------------
// RoPE on Q (scale log2e/sqrt(128) folded in) and K, in place (bf16 bufs,
// fp32 cos/sin).
// ---------------------------------------------------------------------------
__global__ __launch_bounds__(256) void rope_k(u16* __restrict__ qbuf, u16* __restrict__ kbuf,
                                              const float* __restrict__ cosb,
                                              const float* __restrict__ sinb) {
  int g = blockIdx.x * 256 + threadIdx.x;
  u16* base; int s, d0; float scale;
  if (g < 2048 * 32 * 8) {
    int token = g >> 8; int rem = g & 255; int h = rem >> 3; d0 = (rem & 7) * 8;
    base = qbuf + (size_t)token * 4096 + h * 128;
    s = token & 1023;
    scale = (float)(1.4426950408889634 / 11.313708498984761);  // log2e/sqrt(128)
  } else {
    int g2 = g - 2048 * 32 * 8; int token = g2 >> 6; int rem = g2 & 63;
    int h = rem >> 3; d0 = (rem & 7) * 8;
    base = kbuf + (size_t)token * 1024 + h * 128;
    s = token & 1023;
    scale = 1.0f;
  }
  u16x8 x = *(const u16x8*)(base + d0);
  u16x8 y = *(const u16x8*)(base + 64 + d0);
  f32x4 c0 = *(const f32x4*)(cosb + s * 128 + d0);
  f32x4 c1 = *(const f32x4*)(cosb + s * 128 + d0 + 4);
  f32x4 s0 = *(const f32x4*)(sinb + s * 128 + d0);
  f32x4 s1 = *(const f32x4*)(sinb + s * 128 + d0 + 4);
  u16x8 ox, oy;
#pragma unroll
  for (int j = 0; j < 8; j++) {
    float cf = (j < 4) ? c0[j] : c1[j - 4];
    float sf = (j < 4) ? s0[j] : s1[j - 4];
    float xf = b2f(x[j]), yf = b2f(y[j]);
    ox[j] = f2b((xf * cf - yf * sf) * scale);
    oy[j] = f2b((yf * cf + xf * sf) * scale);
  }
  *(u16x8*)(base + d0) = ox;
  *(u16x8*)(base + 64 + d0) = oy;
}

// ---------------------------------------------------------------------------
// Build V^T (bf16) in global: vtg[b][kvh][d(128)][kv(4096)].
// Fresh V from vbuf (bf16); prefix V from vst (fp32, converted).
// ---------------------------------------------------------------------------
__global__ __launch_bounds__(256) void vt_build(const u16* __restrict__ vbuf,
                                                const float* __restrict__ vst,
                                                const int* __restrict__ lut,
                                                u16* __restrict__ vtg) {
  __shared__ __align__(16) u16 Vl[64 * 136];
  int kb = blockIdx.x, kvh = blockIdx.y, b = blockIdx.z;
  int tid = threadIdx.x;
#pragma unroll
  for (int it = 0; it < 4; it++) {
    int chunk = tid + it * 256;
    int srow = chunk >> 4, c = chunk & 15, d0 = c * 8;
    int kvrow = kb * 64 + srow;
    int j4 = kvrow >> 4, r16 = kvrow & 15;
    u16x8 w;
    if (j4 >= FRESH0) {
      w = *(const u16x8*)(vbuf + (size_t)(b * 1024 + kvrow - PREFIX) * 1024 + kvh * 128 + d0);
    } else {
      int p = lut[b * 256 + j4];
      const float* src = vst + (((size_t)p * 8 + kvh) * 16 + r16) * 128 + d0;
      w = cvt8(*(const f32x4*)src, *(const f32x4*)(src + 4));
    }
    *(u16x8*)&Vl[srow * 136 + d0] = w;
  }
  __syncthreads();
#pragma unroll
  for (int it = 0; it < 4; it++) {
    int chunk = tid + it * 256;
    int d = chunk >> 3, s8 = chunk & 7;
    u16x8 w;
#pragma unroll
    for (int j = 0; j < 8; j++) w[j] = Vl[(s8 * 8 + j) * 136 + d];
    *(u16x8*)&vtg[(((size_t)(b * 8 + kvh) * 128) + d) * 4096 + kb * 64 + s8 * 8] = w;
  }
}

// ---------------------------------------------------------------------------
// Flash attention. Block = (qtile of 16, kvh, b); wave w = GQA head kvh*4+w.
// Q pre-scaled by log2e/sqrt(128) -> softmax in exp2 domain.
// ---------------------------------------------------------------------------
__global__ __launch_bounds__(256) void attn_k(const u16* __restrict__ qbuf,
                                              const u16* __restrict__ kbuf,
                                              const float* __restrict__ kst,
                                              const u16* __restrict__ vtg,
                                              const int* __restrict__ lut,
                                              u16* __restrict__ obuf) {
  __shared__ __align__(16) u16 Kl[64 * 136];
  __shared__ __align__(16) u16 Vt[128 * 72];
  __shared__ __align__(16) u16 Pl[4 * 16 * 72];
  int qt = blockIdx.x, kvh = blockIdx.y, b = blockIdx.z;
  int tid = threadIdx.x;
  int wave = tid >> 6, lane = tid & 63;
  int lr = lane & 15, quad = lane >> 4;
  int h = kvh * 4 + wave;
  int qpos0 = PREFIX + qt * 16;

  // read Q first (obuf aliases qbuf; this wave's O region == its Q region)
  bf16x8 qf[4];
  const u16* qp = qbuf + (size_t)(b * 1024 + qt * 16 + lr) * 4096 + h * 128 + quad * 8;
#pragma unroll
  for (int ks = 0; ks < 4; ks++) qf[ks] = asbf(*(const u16x8*)(qp + ks * 32));

  f32x4 Oacc[8];
#pragma unroll
  for (int i = 0; i < 8; i++) Oacc[i] = (f32x4){0.f, 0.f, 0.f, 0.f};
  float m_i[4] = {-1e30f, -1e30f, -1e30f, -1e30f};
  float l_i[4] = {0.f, 0.f, 0.f, 0.f};

  int nkb = (qpos0 + 16 + 63) >> 6;

  for (int kb = 0; kb < nkb; kb++) {
    __syncthreads();
    // ---- stage K (64 x 128): fresh bf16 copy / paged fp32 convert
#pragma unroll
    for (int it = 0; it < 4; it++) {
      int chunk = tid + it * 256;
      int srow = chunk >> 4, c = chunk & 15, d0 = c * 8;
      int kvrow = kb * 64 + srow;
      int j4 = kvrow >> 4, r16 = kvrow & 15;
      u16x8 w;
      if (j4 >= FRESH0) {
        w = *(const u16x8*)(kbuf + (size_t)(b * 1024 + kvrow - PREFIX) * 1024 + kvh * 128 + d0);
      } else {
        int p = lut[b * 256 + j4];
        const float* src = kst + (((size_t)p * 8 + kvh) * 16 + r16) * 128 + d0;
        w = cvt8(*(const f32x4*)src, *(const f32x4*)(src + 4));
      }
      *(u16x8*)&Kl[srow * 136 + d0] = w;
    }
    // ---- stage V^T (128 x 64) from vtg (bf16)
    const u16* vbase = vtg + ((size_t)(b * 8 + kvh) * 128) * 4096 + kb * 64;
#pragma unroll
    for (int it = 0; it < 4; it++) {
      int chunk = tid + it * 256;
      int d = chunk >> 3, c8 = chunk & 7;
      *(u16x8*)&Vt[d * 72 + c8 * 8] = *(const u16x8*)(vbase + (size_t)d * 4096 + c8 * 8);
    }
    __syncthreads();

    // ---- S = Q * K^T (16 q rows x 64 kv) per wave
    f32x4 S[4];
#pragma unroll
    for (int ni = 0; ni < 4; ni++) S[ni] = (f32x4){0.f, 0.f, 0.f, 0.f};
#pragma unroll
    for (int ks = 0; ks < 4; ks++)
#pragma unroll
      for (int ni = 0; ni < 4; ni++) {
        bf16x8 kf = asbf(*(const u16x8*)&Kl[(ni * 16 + lr) * 136 + ks * 32 + quad * 8]);
        S[ni] = __builtin_amdgcn_mfma_f32_16x16x32_bf16(qf[ks], kf, S[ni], 0, 0, 0);
      }

    // ---- causal mask (only near the diagonal)
    if (kb * 64 + 63 > qpos0) {
#pragma unroll
      for (int ni = 0; ni < 4; ni++)
#pragma unroll
        for (int r = 0; r < 4; r++) {
          int kvp = kb * 64 + ni * 16 + lr;
          int qp2 = qpos0 + quad * 4 + r;
          if (kvp > qp2) S[ni][r] = -1e30f;
        }
    }

    // ---- online softmax (row quad*4+r lives in the 16 lanes sharing quad)
    float rmax[4];
#pragma unroll
    for (int r = 0; r < 4; r++)
      rmax[r] = fmaxf(fmaxf(S[0][r], S[1][r]), fmaxf(S[2][r], S[3][r]));
#pragma unroll
    for (int off = 1; off < 16; off <<= 1)
#pragma unroll
      for (int r = 0; r < 4; r++) rmax[r] = fmaxf(rmax[r], __shfl_xor(rmax[r], off));

    float alpha[4];
#pragma unroll
    for (int r = 0; r < 4; r++) {
      float nm = fmaxf(m_i[r], rmax[r]);
      alpha[r] = exp2f(m_i[r] - nm);
      m_i[r] = nm;
    }
    float rsum[4] = {0.f, 0.f, 0.f, 0.f};
#pragma unroll
    for (int ni = 0; ni < 4; ni++)
#pragma unroll
      for (int r = 0; r < 4; r++) {
        float p = exp2f(S[ni][r] - m_i[r]);
        rsum[r] += p;
        Pl[(wave * 16 + quad * 4 + r) * 72 + ni * 16 + lr] = f2b(p);
      }
#pragma unroll
    for (int off = 1; off < 16; off <<= 1)
#pragma unroll
      for (int r = 0; r < 4; r++) rsum[r] += __shfl_xor(rsum[r], off);
#pragma unroll
    for (int r = 0; r < 4; r++) l_i[r] = l_i[r] * alpha[r] + rsum[r];
#pragma unroll
    for (int ni8 = 0; ni8 < 8; ni8++)
#pragma unroll
      for (int r = 0; r < 4; r++) Oacc[ni8][r] *= alpha[r];

    // ---- O += P * V   (P via per-wave LDS strip: C-layout -> A-layout)
#pragma unroll
    for (int k2 = 0; k2 < 2; k2++) {
      bf16x8 pf = asbf(*(const u16x8*)&Pl[(wave * 16 + lr) * 72 + k2 * 32 + quad * 8]);
#pragma unroll
      for (int ni8 = 0; ni8 < 8; ni8++) {
        bf16x8 vf = asbf(*(const u16x8*)&Vt[(ni8 * 16 + lr) * 72 + k2 * 32 + quad * 8]);
        Oacc[ni8] = __builtin_amdgcn_mfma_f32_16x16x32_bf16(pf, vf, Oacc[ni8], 0, 0, 0);
      }
    }
  }

  // ---- epilogue: normalize and store (bf16) to obuf[b][s][h][d]
  float rcp[4];
#pragma unroll
  for (int r = 0; r < 4; r++) rcp[r] = 1.0f / fmaxf(l_i[r], 1e-30f);
#pragma unroll
  for (int ni8 = 0; ni8 < 8; ni8++)
#pragma unroll
    for (int r = 0; r < 4; r++) {
      float o = Oacc[ni8][r] * rcp[r];
      obuf[(size_t)(b * 1024 + qt * 16 + quad * 4 + r) * 4096 + h * 128 + ni8 * 16 + lr] = f2b(o);
    }
}

// ---------------------------------------------------------------------------
extern "C" void kernel_launch(void* const* d_in, const int* in_sizes, int n_in,
                              void* d_out, int out_size, void* d_ws, size_t ws_size,
                              hipStream_t stream) {
  const float* hidden = (const float*)d_in[0];
  const float* Wq = (const float*)d_in[1];
  const float* Wk = (const float*)d_in[2];
  const float* Wv = (const float*)d_in[3];
  const float* Wo = (const float*)d_in[4];
  const float* cosb = (const float*)d_in[5];
  const float* sinb = (const float*)d_in[6];
  const float* kst = (const float*)d_in[7];
  const float* vst = (const float*)d_in[8];
  const int* lut = (const int*)d_in[9];
  float* out = (float*)d_out;

  u16* qbuf = (u16*)d_ws;                       // 2048 x 4096 bf16 (reused as obuf)
  u16* kbuf = qbuf + (size_t)2048 * 4096;       // 2048 x 1024 bf16
  u16* vbuf = kbuf + (size_t)2048 * 1024;       // 2048 x 1024 bf16
  u16* vtg  = vbuf + (size_t)2048 * 1024;       // 16 x 128 x 4096 bf16
  u16* obuf = qbuf;                             // alias: attn reads Q before writing O

  gemm_ff<<<dim3(32, 16), 256, 0, stream>>>(hidden, Wq, qbuf, 4096, 4096);
  gemm_ff<<<dim3(8, 16), 256, 0, stream>>>(hidden, Wk, kbuf, 1024, 4096);
  gemm_ff<<<dim3(8, 16), 256, 0, stream>>>(hidden, Wv, vbuf, 1024, 4096);
  rope_k<<<2560, 256, 0, stream>>>(qbuf, kbuf, cosb, sinb);
  vt_build<<<dim3(64, 8, 2), 256, 0, stream>>>(vbuf, vst, lut, vtg);
  attn_k<<<dim3(64, 8, 2), 256, 0, stream>>>(qbuf, kbuf, kst, vtg, lut, obuf);
  gemm_bf<<<dim3(32, 16), 256, 0, stream>>>(obuf, Wo, out, 4096, 4096);
}

// Round 4
// 968.266 us; speedup vs baseline: 1.4299x; 1.4299x over previous
//
#include <hip/hip_runtime.h>

// ============================================================================
// L4maAttention on MI355X (gfx950) — round 4
// Round-3 passed at 1384us. attn_k (580us) was VALU-bound on in-loop fp32->bf16
// cvt of paged K (35% VALUBusy, MfmaUtil 8.8%). This round:
//  - cvt hidden -> bf16 once (hbuf): all GEMMs get global_load_lds A-side
//  - kf_build: contiguous bf16 K panel (paged fp32 + fresh) built once
//  - vt_build_blk: V^T panel, block-tiled so each 64-kv tile is contiguous
//  - attn32: 32 q-rows/wave (2x MFMA per staging), register prefetch of next
//    KV tile issued before compute -> global latency hidden across barrier
//  - K/V GEMMs merged into one launch via blockIdx.z
// Fast path needs 75.5MB ws; falls back to proven round-3 pipeline if ws_size
// is smaller (runtime branch on a constant -> same work every call).
// ============================================================================

typedef unsigned short u16;
typedef __attribute__((ext_vector_type(8))) unsigned short u16x8;
typedef __attribute__((ext_vector_type(8))) __bf16 bf16x8;
typedef __attribute__((ext_vector_type(4))) float f32x4;

#define PREFIX 3072
#define FRESH0 192   // PREFIX/16

__device__ __forceinline__ float b2f(u16 s) {
  union { unsigned u; float f; } v; v.u = ((unsigned)s) << 16; return v.f;
}
__device__ __forceinline__ u16 f2b(float f) {
  union { float f; unsigned u; } v; v.f = f;
  return (u16)((v.u + 0x7FFFu + ((v.u >> 16) & 1u)) >> 16);
}
__device__ __forceinline__ bf16x8 asbf(u16x8 u) { return __builtin_bit_cast(bf16x8, u); }
__device__ __forceinline__ u16x8 cvt8(f32x4 a, f32x4 b) {
  u16x8 r;
#pragma unroll
  for (int i = 0; i < 4; i++) { r[i] = f2b(a[i]); r[4 + i] = f2b(b[i]); }
  return r;
}
__device__ __forceinline__ void gll16(const u16* g, u16* l) {
  __builtin_amdgcn_global_load_lds(
      (const __attribute__((address_space(1))) unsigned*)g,
      (__attribute__((address_space(3))) unsigned*)l, 16, 0, 0);
}

// ---------------------------------------------------------------------------
// fp32 -> bf16 bulk convert (n8 = element count / 8)
// ---------------------------------------------------------------------------
__global__ __launch_bounds__(256) void cvt_bf16(const float* __restrict__ src,
                                                u16* __restrict__ dst, int n8) {
  int i = blockIdx.x * 256 + threadIdx.x;
  if (i >= n8) return;
  const float* s = src + (size_t)i * 8;
  *(u16x8*)(dst + (size_t)i * 8) = cvt8(*(const f32x4*)s, *(const f32x4*)(s + 4));
}

// ---------------------------------------------------------------------------
// GEMM A(bf16)[M][K] * W(f32)[N][K]^T -> C[M][N].  A via global_load_lds,
// W converted inline. F32OUT selects output dtype. blockIdx.z selects (W,C)
// pair so K/V projections share one launch.
// ---------------------------------------------------------------------------
template <int F32OUT>
__global__ __launch_bounds__(256) void gemm_ab(const u16* __restrict__ A,
                                               const float* __restrict__ W0,
                                               const float* __restrict__ W1,
                                               void* __restrict__ C0v,
                                               void* __restrict__ C1v,
                                               int N, int K) {
  const float* W = blockIdx.z ? W1 : W0;
  void* Cv = blockIdx.z ? C1v : C0v;
  __shared__ __align__(16) u16 lA[128 * 32];
  __shared__ __align__(16) u16 lB[128 * 32];
  const int tid = threadIdx.x;
  const int wave = tid >> 6, lane = tid & 63;
  const int lr = lane & 15, quad = lane >> 4;
  const int m0 = blockIdx.y * 128, n0 = blockIdx.x * 128;
  const int wm = (wave & 1) * 64, wn = (wave >> 1) * 64;

  const u16* aS0 = A + (size_t)(m0 + (tid >> 2)) * K + (tid & 3) * 8;
  const u16* aS1 = aS0 + (size_t)64 * K;
  const float* bP0 = W + (size_t)(n0 + (tid >> 2)) * K + (tid & 3) * 8;
  const float* bP1 = bP0 + (size_t)64 * K;
  u16* lA0 = lA + wave * 512;   // wave-uniform LDS base for global_load_lds
  u16* lA1 = lA + 2048 + wave * 512;
  u16* lb0 = &lB[(tid >> 2) * 32 + (tid & 3) * 8];
  u16* lb1 = lb0 + 64 * 32;

  f32x4 acc[4][4];
#pragma unroll
  for (int i = 0; i < 4; i++)
#pragma unroll
    for (int j = 0; j < 4; j++) acc[i][j] = (f32x4){0.f, 0.f, 0.f, 0.f};

  for (int k0 = 0; k0 < K; k0 += 32) {
    f32x4 b0 = *(const f32x4*)bP0, b0b = *(const f32x4*)(bP0 + 4);
    f32x4 b1 = *(const f32x4*)bP1, b1b = *(const f32x4*)(bP1 + 4);
    bP0 += 32; bP1 += 32;
    __syncthreads();
    gll16(aS0, lA0); gll16(aS1, lA1);
    aS0 += 32; aS1 += 32;
    *(u16x8*)lb0 = cvt8(b0, b0b);
    *(u16x8*)lb1 = cvt8(b1, b1b);
    __syncthreads();
    bf16x8 af[4], bfr[4];
#pragma unroll
    for (int i = 0; i < 4; i++)
      af[i] = asbf(*(const u16x8*)&lA[(wm + i * 16 + lr) * 32 + quad * 8]);
#pragma unroll
    for (int i = 0; i < 4; i++)
      bfr[i] = asbf(*(const u16x8*)&lB[(wn + i * 16 + lr) * 32 + quad * 8]);
#pragma unroll
    for (int mi = 0; mi < 4; mi++)
#pragma unroll
      for (int ni = 0; ni < 4; ni++)
        acc[mi][ni] = __builtin_amdgcn_mfma_f32_16x16x32_bf16(af[mi], bfr[ni], acc[mi][ni], 0, 0, 0);
  }

#pragma unroll
  for (int mi = 0; mi < 4; mi++)
#pragma unroll
    for (int ni = 0; ni < 4; ni++) {
      int row = m0 + wm + mi * 16 + quad * 4;
      int col = n0 + wn + ni * 16 + lr;
#pragma unroll
      for (int r = 0; r < 4; r++) {
        if (F32OUT) ((float*)Cv)[(size_t)(row + r) * N + col] = acc[mi][ni][r];
        else ((u16*)Cv)[(size_t)(row + r) * N + col] = f2b(acc[mi][ni][r]);
      }
    }
}

// ---------------------------------------------------------------------------
// RoPE on Q (scale log2e/sqrt(128) folded) and K, in place (bf16, fp32 cos/sin)
// ---------------------------------------------------------------------------
__global__ __launch_bounds__(256) void rope_k(u16* __restrict__ qbuf, u16* __restrict__ kbuf,
                                              const float* __restrict__ cosb,
                                              const float* __restrict__ sinb) {
  int g = blockIdx.x * 256 + threadIdx.x;
  u16* base; int s, d0; float scale;
  if (g < 2048 * 32 * 8) {
    int token = g >> 8; int rem = g & 255; int h = rem >> 3; d0 = (rem & 7) * 8;
    base = qbuf + (size_t)token * 4096 + h * 128;
    s = token & 1023;
    scale = (float)(1.4426950408889634 / 11.313708498984761);
  } else {
    int g2 = g - 2048 * 32 * 8; int token = g2 >> 6; int rem = g2 & 63;
    int h = rem >> 3; d0 = (rem & 7) * 8;
    base = kbuf + (size_t)token * 1024 + h * 128;
    s = token & 1023;
    scale = 1.0f;
  }
  u16x8 x = *(const u16x8*)(base + d0);
  u16x8 y = *(const u16x8*)(base + 64 + d0);
  f32x4 c0 = *(const f32x4*)(cosb + s * 128 + d0);
  f32x4 c1 = *(const f32x4*)(cosb + s * 128 + d0 + 4);
  f32x4 s0 = *(const f32x4*)(sinb + s * 128 + d0);
  f32x4 s1 = *(const f32x4*)(sinb + s * 128 + d0 + 4);
  u16x8 ox, oy;
#pragma unroll
  for (int j = 0; j < 8; j++) {
    float cf = (j < 4) ? c0[j] : c1[j - 4];
    float sf = (j < 4) ? s0[j] : s1[j - 4];
    float xf = b2f(x[j]), yf = b2f(y[j]);
    ox[j] = f2b((xf * cf - yf * sf) * scale);
    oy[j] = f2b((yf * cf + xf * sf) * scale);
  }
  *(u16x8*)(base + d0) = ox;
  *(u16x8*)(base + 64 + d0) = oy;
}

// ---------------------------------------------------------------------------
// Build contiguous bf16 K panel: kfull[b][kvh][kv 4096][d 128].
// Block = one 16-row kv block (j4 = blockIdx.x). 256 thr x u16x8 = 4KB.
// ---------------------------------------------------------------------------
__global__ __launch_bounds__(256) void kf_build(const u16* __restrict__ kbuf,
                                                const float* __restrict__ kst,
                                                const int* __restrict__ lut,
                                                u16* __restrict__ kfull) {
  int j4 = blockIdx.x, kvh = blockIdx.y, b = blockIdx.z;
  int tid = threadIdx.x;
  int r16 = tid >> 4, d0 = (tid & 15) * 8;
  int kvrow = j4 * 16 + r16;
  u16x8 w;
  if (j4 >= FRESH0) {
    w = *(const u16x8*)(kbuf + (size_t)(b * 1024 + kvrow - PREFIX) * 1024 + kvh * 128 + d0);
  } else {
    int p = lut[b * 256 + j4];
    const float* src = kst + (((size_t)p * 8 + kvh) * 16 + r16) * 128 + d0;
    w = cvt8(*(const f32x4*)src, *(const f32x4*)(src + 4));
  }
  *(u16x8*)(kfull + (((size_t)(b * 8 + kvh) * 4096) + kvrow) * 128 + d0) = w;
}

// ---------------------------------------------------------------------------
// Build block-tiled V^T: vtg[b][kvh][kb 64][d 128][kv 64] (each tile 16KB
// contiguous so attention staging is perfectly coalesced).
// ---------------------------------------------------------------------------
__global__ __launch_bounds__(256) void vt_build_blk(const u16* __restrict__ vbuf,
                                                    const float* __restrict__ vst,
                                                    const int* __restrict__ lut,
                                                    u16* __restrict__ vtg) {
  __shared__ __align__(16) u16 Vl[64 * 136];
  int kb = blockIdx.x, kvh = blockIdx.y, b = blockIdx.z;
  int tid = threadIdx.x;
#pragma unroll
  for (int it = 0; it < 4; it++) {
    int chunk = tid + it * 256;
    int srow = chunk >> 4, d0 = (chunk & 15) * 8;
    int kvrow = kb * 64 + srow;
    int j4 = kvrow >> 4, r16 = kvrow & 15;
    u16x8 w;
    if (j4 >= FRESH0) {
      w = *(const u16x8*)(vbuf + (size_t)(b * 1024 + kvrow - PREFIX) * 1024 + kvh * 128 + d0);
    } else {
      int p = lut[b * 256 + j4];
      const float* src = vst + (((size_t)p * 8 + kvh) * 16 + r16) * 128 + d0;
      w = cvt8(*(const f32x4*)src, *(const f32x4*)(src + 4));
    }
    *(u16x8*)&Vl[srow * 136 + d0] = w;
  }
  __syncthreads();
  u16* outp = vtg + (((size_t)(b * 8 + kvh) * 64) + kb) * 8192;
#pragma unroll
  for (int it = 0; it < 4; it++) {
    int chunk = tid + it * 256;
    int d = chunk >> 3, s8 = chunk & 7;
    u16x8 w;
#pragma unroll
    for (int j = 0; j < 8; j++) w[j] = Vl[(s8 * 8 + j) * 136 + d];
    *(u16x8*)(outp + d * 64 + s8 * 8) = w;
  }
}

// ---------------------------------------------------------------------------
// Flash attention, 32 q-rows per wave. Block = (qt32, kvh, b); wave = head.
// Register prefetch of next KV tile overlaps compute.
// ---------------------------------------------------------------------------
__global__ __launch_bounds__(256, 2) void attn32(const u16* __restrict__ qbuf,
                                                 const u16* __restrict__ kfull,
                                                 const u16* __restrict__ vtg,
                                                 u16* __restrict__ obuf) {
  __shared__ __align__(16) u16 Kl[64 * 136];
  __shared__ __align__(16) u16 Vt[128 * 72];
  __shared__ __align__(16) u16 Pl[4 * 32 * 72];
  int qt = blockIdx.x, kvh = blockIdx.y, b = blockIdx.z;
  int tid = threadIdx.x;
  int wave = tid >> 6, lane = tid & 63;
  int lr = lane & 15, quad = lane >> 4;
  int h = kvh * 4 + wave;
  int qpos0 = PREFIX + qt * 32;

  // Q fragments: 2 row-tiles x 4 k-chunks (read before O overwrite; obuf==qbuf)
  bf16x8 qf[2][4];
#pragma unroll
  for (int rt = 0; rt < 2; rt++) {
    const u16* qp = qbuf + (size_t)(b * 1024 + qt * 32 + rt * 16 + lr) * 4096 + h * 128 + quad * 8;
#pragma unroll
    for (int ks = 0; ks < 4; ks++) qf[rt][ks] = asbf(*(const u16x8*)(qp + ks * 32));
  }

  f32x4 Oacc[2][8];
#pragma unroll
  for (int rt = 0; rt < 2; rt++)
#pragma unroll
    for (int i = 0; i < 8; i++) Oacc[rt][i] = (f32x4){0.f, 0.f, 0.f, 0.f};
  float m_i[2][4], l_i[2][4];
#pragma unroll
  for (int rt = 0; rt < 2; rt++)
#pragma unroll
    for (int r = 0; r < 4; r++) { m_i[rt][r] = -1e30f; l_i[rt][r] = 0.f; }

  int nkb = (qpos0 + 32 + 63) >> 6;
  const u16* kpan = kfull + ((size_t)(b * 8 + kvh) * 4096) * 128;
  const u16* vpan = vtg + ((size_t)(b * 8 + kvh) * 64) * 8192;

  u16x8 kreg[4], vreg[4];
#pragma unroll
  for (int it = 0; it < 4; it++) {
    kreg[it] = *(const u16x8*)(kpan + (size_t)(tid + it * 256) * 8);
    vreg[it] = *(const u16x8*)(vpan + (size_t)(tid + it * 256) * 8);
  }

  for (int kb = 0; kb < nkb; kb++) {
    __syncthreads();   // previous iteration's LDS reads complete
#pragma unroll
    for (int it = 0; it < 4; it++) {
      int chunk = tid + it * 256;
      *(u16x8*)&Kl[(chunk >> 4) * 136 + (chunk & 15) * 8] = kreg[it];
      *(u16x8*)&Vt[(chunk >> 3) * 72 + (chunk & 7) * 8] = vreg[it];
    }
    __syncthreads();

    // prefetch next tile (overlaps with compute below)
    if (kb + 1 < nkb) {
      const u16* kp = kpan + (size_t)(kb + 1) * 8192;
      const u16* vp = vpan + (size_t)(kb + 1) * 8192;
#pragma unroll
      for (int it = 0; it < 4; it++) {
        kreg[it] = *(const u16x8*)(kp + (size_t)(tid + it * 256) * 8);
        vreg[it] = *(const u16x8*)(vp + (size_t)(tid + it * 256) * 8);
      }
    }

    // ---- S = Q K^T : 2 row-tiles x 64 kv, kf shared across row-tiles
    f32x4 S[2][4];
#pragma unroll
    for (int rt = 0; rt < 2; rt++)
#pragma unroll
      for (int ni = 0; ni < 4; ni++) S[rt][ni] = (f32x4){0.f, 0.f, 0.f, 0.f};
#pragma unroll
    for (int ks = 0; ks < 4; ks++)
#pragma unroll
      for (int ni = 0; ni < 4; ni++) {
        bf16x8 kf = asbf(*(const u16x8*)&Kl[(ni * 16 + lr) * 136 + ks * 32 + quad * 8]);
        S[0][ni] = __builtin_amdgcn_mfma_f32_16x16x32_bf16(qf[0][ks], kf, S[0][ni], 0, 0, 0);
        S[1][ni] = __builtin_amdgcn_mfma_f32_16x16x32_bf16(qf[1][ks], kf, S[1][ni], 0, 0, 0);
      }

    // ---- causal mask near diagonal
#pragma unroll
    for (int rt = 0; rt < 2; rt++) {
      int rbase = qpos0 + rt * 16;
      if (kb * 64 + 63 > rbase) {
#pragma unroll
        for (int ni = 0; ni < 4; ni++)
#pragma unroll
          for (int r = 0; r < 4; r++) {
            int kvp = kb * 64 + ni * 16 + lr;
            if (kvp > rbase + quad * 4 + r) S[rt][ni][r] = -1e30f;
          }
      }
    }

    // ---- online softmax + P into per-wave LDS strip
#pragma unroll
    for (int rt = 0; rt < 2; rt++) {
      float rmax[4];
#pragma unroll
      for (int r = 0; r < 4; r++)
        rmax[r] = fmaxf(fmaxf(S[rt][0][r], S[rt][1][r]), fmaxf(S[rt][2][r], S[rt][3][r]));
#pragma unroll
      for (int off = 1; off < 16; off <<= 1)
#pragma unroll
        for (int r = 0; r < 4; r++) rmax[r] = fmaxf(rmax[r], __shfl_xor(rmax[r], off));
      float alpha[4];
#pragma unroll
      for (int r = 0; r < 4; r++) {
        float nm = fmaxf(m_i[rt][r], rmax[r]);
        alpha[r] = exp2f(m_i[rt][r] - nm);
        m_i[rt][r] = nm;
      }
      float rsum[4] = {0.f, 0.f, 0.f, 0.f};
#pragma unroll
      for (int ni = 0; ni < 4; ni++)
#pragma unroll
        for (int r = 0; r < 4; r++) {
          float p = exp2f(S[rt][ni][r] - m_i[rt][r]);
          rsum[r] += p;
          Pl[(wave * 32 + rt * 16 + quad * 4 + r) * 72 + ni * 16 + lr] = f2b(p);
        }
#pragma unroll
      for (int off = 1; off < 16; off <<= 1)
#pragma unroll
        for (int r = 0; r < 4; r++) rsum[r] += __shfl_xor(rsum[r], off);
#pragma unroll
      for (int r = 0; r < 4; r++) l_i[rt][r] = l_i[rt][r] * alpha[r] + rsum[r];
#pragma unroll
      for (int ni8 = 0; ni8 < 8; ni8++)
#pragma unroll
        for (int r = 0; r < 4; r++) Oacc[rt][ni8][r] *= alpha[r];
    }

    // ---- O += P V, vf shared across row-tiles
#pragma unroll
    for (int k2 = 0; k2 < 2; k2++) {
      bf16x8 pf0 = asbf(*(const u16x8*)&Pl[(wave * 32 + lr) * 72 + k2 * 32 + quad * 8]);
      bf16x8 pf1 = asbf(*(const u16x8*)&Pl[(wave * 32 + 16 + lr) * 72 + k2 * 32 + quad * 8]);
#pragma unroll
      for (int ni8 = 0; ni8 < 8; ni8++) {
        bf16x8 vf = asbf(*(const u16x8*)&Vt[(ni8 * 16 + lr) * 72 + k2 * 32 + quad * 8]);
        Oacc[0][ni8] = __builtin_amdgcn_mfma_f32_16x16x32_bf16(pf0, vf, Oacc[0][ni8], 0, 0, 0);
        Oacc[1][ni8] = __builtin_amdgcn_mfma_f32_16x16x32_bf16(pf1, vf, Oacc[1][ni8], 0, 0, 0);
      }
    }
  }

  // ---- epilogue
#pragma unroll
  for (int rt = 0; rt < 2; rt++) {
    float rcp[4];
#pragma unroll
    for (int r = 0; r < 4; r++) rcp[r] = 1.0f / fmaxf(l_i[rt][r], 1e-30f);
#pragma unroll
    for (int ni8 = 0; ni8 < 8; ni8++)
#pragma unroll
      for (int r = 0; r < 4; r++) {
        float o = Oacc[rt][ni8][r] * rcp[r];
        obuf[(size_t)(b * 1024 + qt * 32 + rt * 16 + quad * 4 + r) * 4096 + h * 128 + ni8 * 16 + lr] = f2b(o);
      }
  }
}

// ============================================================================
// Fallback pipeline (round-3, proven at 42MB ws) — used when ws_size < fast
// path's requirement.
// ============================================================================
__global__ __launch_bounds__(256) void gemm_ff(const float* __restrict__ A,
                                               const float* __restrict__ W,
                                               u16* __restrict__ C,
                                               int N, int K) {
  __shared__ __align__(16) u16 lA[128 * 32];
  __shared__ __align__(16) u16 lB[128 * 32];
  const int tid = threadIdx.x;
  const int wave = tid >> 6, lane = tid & 63;
  const int lr = lane & 15, quad = lane >> 4;
  const int m0 = blockIdx.y * 128, n0 = blockIdx.x * 128;
  const int wm = (wave & 1) * 64, wn = (wave >> 1) * 64;
  const float* aP0 = A + (size_t)(m0 + (tid >> 2)) * K + (tid & 3) * 8;
  const float* aP1 = aP0 + (size_t)64 * K;
  const float* bP0 = W + (size_t)(n0 + (tid >> 2)) * K + (tid & 3) * 8;
  const float* bP1 = bP0 + (size_t)64 * K;
  u16* la0 = &lA[(tid >> 2) * 32 + (tid & 3) * 8];
  u16* la1 = la0 + 64 * 32;
  u16* lb0 = &lB[(tid >> 2) * 32 + (tid & 3) * 8];
  u16* lb1 = lb0 + 64 * 32;
  f32x4 acc[4][4];
#pragma unroll
  for (int i = 0; i < 4; i++)
#pragma unroll
    for (int j = 0; j < 4; j++) acc[i][j] = (f32x4){0.f, 0.f, 0.f, 0.f};
  for (int k0 = 0; k0 < K; k0 += 32) {
    f32x4 a0 = *(const f32x4*)aP0, a0b = *(const f32x4*)(aP0 + 4);
    f32x4 a1 = *(const f32x4*)aP1, a1b = *(const f32x4*)(aP1 + 4);
    f32x4 b0 = *(const f32x4*)bP0, b0b = *(const f32x4*)(bP0 + 4);
    f32x4 b1 = *(const f32x4*)bP1, b1b = *(const f32x4*)(bP1 + 4);
    aP0 += 32; aP1 += 32; bP0 += 32; bP1 += 32;
    __syncthreads();
    *(u16x8*)la0 = cvt8(a0, a0b);
    *(u16x8*)la1 = cvt8(a1, a1b);
    *(u16x8*)lb0 = cvt8(b0, b0b);
    *(u16x8*)lb1 = cvt8(b1, b1b);
    __syncthreads();
    bf16x8 af[4], bfr[4];
#pragma unroll
    for (int i = 0; i < 4; i++)
      af[i] = asbf(*(const u16x8*)&lA[(wm + i * 16 + lr) * 32 + quad * 8]);
#pragma unroll
    for (int i = 0; i < 4; i++)
      bfr[i] = asbf(*(const u16x8*)&lB[(wn + i * 16 + lr) * 32 + quad * 8]);
#pragma unroll
    for (int mi = 0; mi < 4; mi++)
#pragma unroll
      for (int ni = 0; ni < 4; ni++)
        acc[mi][ni] = __builtin_amdgcn_mfma_f32_16x16x32_bf16(af[mi], bfr[ni], acc[mi][ni], 0, 0, 0);
  }
#pragma unroll
  for (int mi = 0; mi < 4; mi++)
#pragma unroll
    for (int ni = 0; ni < 4; ni++) {
      int row = m0 + wm + mi * 16 + quad * 4;
      int col = n0 + wn + ni * 16 + lr;
#pragma unroll
      for (int r = 0; r < 4; r++) C[(size_t)(row + r) * N + col] = f2b(acc[mi][ni][r]);
    }
}

__global__ __launch_bounds__(256) void vt_build_flat(const u16* __restrict__ vbuf,
                                                     const float* __restrict__ vst,
                                                     const int* __restrict__ lut,
                                                     u16* __restrict__ vtg) {
  __shared__ __align__(16) u16 Vl[64 * 136];
  int kb = blockIdx.x, kvh = blockIdx.y, b = blockIdx.z;
  int tid = threadIdx.x;
#pragma unroll
  for (int it = 0; it < 4; it++) {
    int chunk = tid + it * 256;
    int srow = chunk >> 4, d0 = (chunk & 15) * 8;
    int kvrow = kb * 64 + srow;
    int j4 = kvrow >> 4, r16 = kvrow & 15;
    u16x8 w;
    if (j4 >= FRESH0) {
      w = *(const u16x8*)(vbuf + (size_t)(b * 1024 + kvrow - PREFIX) * 1024 + kvh * 128 + d0);
    } else {
      int p = lut[b * 256 + j4];
      const float* src = vst + (((size_t)p * 8 + kvh) * 16 + r16) * 128 + d0;
      w = cvt8(*(const f32x4*)src, *(const f32x4*)(src + 4));
    }
    *(u16x8*)&Vl[srow * 136 + d0] = w;
  }
  __syncthreads();
#pragma unroll
  for (int it = 0; it < 4; it++) {
    int chunk = tid + it * 256;
    int d = chunk >> 3, s8 = chunk & 7;
    u16x8 w;
#pragma unroll
    for (int j = 0; j < 8; j++) w[j] = Vl[(s8 * 8 + j) * 136 + d];
    *(u16x8*)&vtg[(((size_t)(b * 8 + kvh) * 128) + d) * 4096 + kb * 64 + s8 * 8] = w;
  }
}

__global__ __launch_bounds__(256) void attn_k(const u16* __restrict__ qbuf,
                                              const u16* __restrict__ kbuf,
                                              const float* __restrict__ kst,
                                              const u16* __restrict__ vtg,
                                              const int* __restrict__ lut,
                                              u16* __restrict__ obuf) {
  __shared__ __align__(16) u16 Kl[64 * 136];
  __shared__ __align__(16) u16 Vt[128 * 72];
  __shared__ __align__(16) u16 Pl[4 * 16 * 72];
  int qt = blockIdx.x, kvh = blockIdx.y, b = blockIdx.z;
  int tid = threadIdx.x;
  int wave = tid >> 6, lane = tid & 63;
  int lr = lane & 15, quad = lane >> 4;
  int h = kvh * 4 + wave;
  int qpos0 = PREFIX + qt * 16;
  bf16x8 qf[4];
  const u16* qp = qbuf + (size_t)(b * 1024 + qt * 16 + lr) * 4096 + h * 128 + quad * 8;
#pragma unroll
  for (int ks = 0; ks < 4; ks++) qf[ks] = asbf(*(const u16x8*)(qp + ks * 32));
  f32x4 Oacc[8];
#pragma unroll
  for (int i = 0; i < 8; i++) Oacc[i] = (f32x4){0.f, 0.f, 0.f, 0.f};
  float m_i[4] = {-1e30f, -1e30f, -1e30f, -1e30f};
  float l_i[4] = {0.f, 0.f, 0.f, 0.f};
  int nkb = (qpos0 + 16 + 63) >> 6;
  for (int kb = 0; kb < nkb; kb++) {
    __syncthreads();
#pragma unroll
    for (int it = 0; it < 4; it++) {
      int chunk = tid + it * 256;
      int srow = chunk >> 4, d0 = (chunk & 15) * 8;
      int kvrow = kb * 64 + srow;
      int j4 = kvrow >> 4, r16 = kvrow & 15;
      u16x8 w;
      if (j4 >= FRESH0) {
        w = *(const u16x8*)(kbuf + (size_t)(b * 1024 + kvrow - PREFIX) * 1024 + kvh * 128 + d0);
      } else {
        int p = lut[b * 256 + j4];
        const float* src = kst + (((size_t)p * 8 + kvh) * 16 + r16) * 128 + d0;
        w = cvt8(*(const f32x4*)src, *(const f32x4*)(src + 4));
      }
      *(u16x8*)&Kl[srow * 136 + d0] = w;
    }
    const u16* vbase = vtg + ((size_t)(b * 8 + kvh) * 128) * 4096 + kb * 64;
#pragma unroll
    for (int it = 0; it < 4; it++) {
      int chunk = tid + it * 256;
      int d = chunk >> 3, c8 = chunk & 7;
      *(u16x8*)&Vt[d * 72 + c8 * 8] = *(const u16x8*)(vbase + (size_t)d * 4096 + c8 * 8);
    }
    __syncthreads();
    f32x4 S[4];
#pragma unroll
    for (int ni = 0; ni < 4; ni++) S[ni] = (f32x4){0.f, 0.f, 0.f, 0.f};
#pragma unroll
    for (int ks = 0; ks < 4; ks++)
#pragma unroll
      for (int ni = 0; ni < 4; ni++) {
        bf16x8 kf = asbf(*(const u16x8*)&Kl[(ni * 16 + lr) * 136 + ks * 32 + quad * 8]);
        S[ni] = __builtin_amdgcn_mfma_f32_16x16x32_bf16(qf[ks], kf, S[ni], 0, 0, 0);
      }
    if (kb * 64 + 63 > qpos0) {
#pragma unroll
      for (int ni = 0; ni < 4; ni++)
#pragma unroll
        for (int r = 0; r < 4; r++) {
          int kvp = kb * 64 + ni * 16 + lr;
          if (kvp > qpos0 + quad * 4 + r) S[ni][r] = -1e30f;
        }
    }
    float rmax[4];
#pragma unroll
    for (int r = 0; r < 4; r++)
      rmax[r] = fmaxf(fmaxf(S[0][r], S[1][r]), fmaxf(S[2][r], S[3][r]));
#pragma unroll
    for (int off = 1; off < 16; off <<= 1)
#pragma unroll
      for (int r = 0; r < 4; r++) rmax[r] = fmaxf(rmax[r], __shfl_xor(rmax[r], off));
    float alpha[4];
#pragma unroll
    for (int r = 0; r < 4; r++) {
      float nm = fmaxf(m_i[r], rmax[r]);
      alpha[r] = exp2f(m_i[r] - nm);
      m_i[r] = nm;
    }
    float rsum[4] = {0.f, 0.f, 0.f, 0.f};
#pragma unroll
    for (int ni = 0; ni < 4; ni++)
#pragma unroll
      for (int r = 0; r < 4; r++) {
        float p = exp2f(S[ni][r] - m_i[r]);
        rsum[r] += p;
        Pl[(wave * 16 + quad * 4 + r) * 72 + ni * 16 + lr] = f2b(p);
      }
#pragma unroll
    for (int off = 1; off < 16; off <<= 1)
#pragma unroll
      for (int r = 0; r < 4; r++) rsum[r] += __shfl_xor(rsum[r], off);
#pragma unroll
    for (int r = 0; r < 4; r++) l_i[r] = l_i[r] * alpha[r] + rsum[r];
#pragma unroll
    for (int ni8 = 0; ni8 < 8; ni8++)
#pragma unroll
      for (int r = 0; r < 4; r++) Oacc[ni8][r] *= alpha[r];
#pragma unroll
    for (int k2 = 0; k2 < 2; k2++) {
      bf16x8 pf = asbf(*(const u16x8*)&Pl[(wave * 16 + lr) * 72 + k2 * 32 + quad * 8]);
#pragma unroll
      for (int ni8 = 0; ni8 < 8; ni8++) {
        bf16x8 vf = asbf(*(const u16x8*)&Vt[(ni8 * 16 + lr) * 72 + k2 * 32 + quad * 8]);
        Oacc[ni8] = __builtin_amdgcn_mfma_f32_16x16x32_bf16(pf, vf, Oacc[ni8], 0, 0, 0);
      }
    }
  }
  float rcp[4];
#pragma unroll
  for (int r = 0; r < 4; r++) rcp[r] = 1.0f / fmaxf(l_i[r], 1e-30f);
#pragma unroll
  for (int ni8 = 0; ni8 < 8; ni8++)
#pragma unroll
    for (int r = 0; r < 4; r++) {
      float o = Oacc[ni8][r] * rcp[r];
      obuf[(size_t)(b * 1024 + qt * 16 + quad * 4 + r) * 4096 + h * 128 + ni8 * 16 + lr] = f2b(o);
    }
}

// ---------------------------------------------------------------------------
extern "C" void kernel_launch(void* const* d_in, const int* in_sizes, int n_in,
                              void* d_out, int out_size, void* d_ws, size_t ws_size,
                              hipStream_t stream) {
  const float* hidden = (const float*)d_in[0];
  const float* Wq = (const float*)d_in[1];
  const float* Wk = (const float*)d_in[2];
  const float* Wv = (const float*)d_in[3];
  const float* Wo = (const float*)d_in[4];
  const float* cosb = (const float*)d_in[5];
  const float* sinb = (const float*)d_in[6];
  const float* kst = (const float*)d_in[7];
  const float* vst = (const float*)d_in[8];
  const int* lut = (const int*)d_in[9];
  float* out = (float*)d_out;

  // fast-path workspace layout (u16 elements)
  const size_t E_H = (size_t)2048 * 4096;   // hbuf / qbuf
  const size_t E_K = (size_t)2048 * 1024;   // kbuf / vbuf
  const size_t E_P = (size_t)16 * 128 * 4096;  // vtg / kfull
  const size_t need_fast = (2 * E_H + 2 * E_K + 2 * E_P) * sizeof(u16);

  if (ws_size >= need_fast) {
    u16* hbuf = (u16*)d_ws;
    u16* qbuf = hbuf + E_H;
    u16* kbuf = qbuf + E_H;
    u16* vbuf = kbuf + E_K;
    u16* vtg = vbuf + E_K;
    u16* kfull = vtg + E_P;
    u16* obuf = qbuf;  // attn reads Q before writing O

    cvt_bf16<<<4096, 256, 0, stream>>>(hidden, hbuf, (int)(E_H / 8));
    gemm_ab<0><<<dim3(32, 16, 1), 256, 0, stream>>>(hbuf, Wq, nullptr, qbuf, nullptr, 4096, 4096);
    gemm_ab<0><<<dim3(8, 16, 2), 256, 0, stream>>>(hbuf, Wk, Wv, kbuf, vbuf, 1024, 4096);
    rope_k<<<2560, 256, 0, stream>>>(qbuf, kbuf, cosb, sinb);
    kf_build<<<dim3(256, 8, 2), 256, 0, stream>>>(kbuf, kst, lut, kfull);
    vt_build_blk<<<dim3(64, 8, 2), 256, 0, stream>>>(vbuf, vst, lut, vtg);
    attn32<<<dim3(32, 8, 2), 256, 0, stream>>>(qbuf, kfull, vtg, obuf);
    gemm_ab<1><<<dim3(32, 16, 1), 256, 0, stream>>>(obuf, Wo, nullptr, out, nullptr, 4096, 4096);
  } else {
    // round-3 proven fallback (42MB)
    u16* qbuf = (u16*)d_ws;
    u16* kbuf = qbuf + E_H;
    u16* vbuf = kbuf + E_K;
    u16* vtg = vbuf + E_K;
    u16* obuf = qbuf;

    gemm_ff<<<dim3(32, 16), 256, 0, stream>>>(hidden, Wq, qbuf, 4096, 4096);
    gemm_ff<<<dim3(8, 16), 256, 0, stream>>>(hidden, Wk, kbuf, 1024, 4096);
    gemm_ff<<<dim3(8, 16), 256, 0, stream>>>(hidden, Wv, vbuf, 1024, 4096);
    rope_k<<<2560, 256, 0, stream>>>(qbuf, kbuf, cosb, sinb);
    vt_build_flat<<<dim3(64, 8, 2), 256, 0, stream>>>(vbuf, vst, lut, vtg);
    attn_k<<<dim3(64, 8, 2), 256, 0, stream>>>(qbuf, kbuf, kst, vtg, lut, obuf);
    gemm_ab<1><<<dim3(32, 16, 1), 256, 0, stream>>>(obuf, Wo, nullptr, out, nullptr, 4096, 4096);
  }
}